// Round 6
// baseline (98.997 us; speedup 1.0000x reference)
//
#include <hip/hip_runtime.h>
#include <math.h>

// Problem constants
#define BB    16      // batch
#define CC    64      // channels
#define HW    441     // h*w
#define QP    448     // HW padded to 28 tiles of 16
#define NCLS  10
#define MM    2205
#define MP2   2304    // m padded to 144 tiles of 16
#define CH_T  8       // m-tiles per chunk = 4 pairs, one pair per wave
#define CH_B  (CH_T * 16 * CC * 2)   // 16384 bytes per chunk
#define NCH   9       // chunks per m-half (72 tiles each)
#define NQT   4       // q-tiles per block (64 queries)

typedef _Float16 half8 __attribute__((ext_vector_type(8)));
typedef float   float4_ __attribute__((ext_vector_type(4)));

// s_waitcnt with vmcnt(n), lgkmcnt/expcnt = no-wait (gfx9 encoding)
#define WAIT_VMCNT(n) __builtin_amdgcn_s_waitcnt(0x0F70 | (n))

// async global->LDS 16B per lane; lds dest = wave-uniform base + lane*16
#define GLDS16(g, l) __builtin_amdgcn_global_load_lds(                         \
    (const __attribute__((address_space(1))) unsigned int*)(const void*)(g),   \
    (__attribute__((address_space(3))) unsigned int*)(void*)(l), 16, 0, 0)

// sorted top-3 insert (a0>=a1>=a2): 3 ops via med3
__device__ __forceinline__ void ins3(float d, float& a0, float& a1, float& a2) {
    float n0 = fmaxf(d, a0);
    float n1 = __builtin_amdgcn_fmed3f(d, a0, a1);
    float n2 = __builtin_amdgcn_fmed3f(d, a1, a2);
    a0 = n0; a1 = n1; a2 = n2;
}

// ---- fused prep: normalize queries (linear fp16) + supports (fp16, XOR-swizzled
// piece order) with LDS-transposed fully-coalesced 4KB block stores ----
__global__ __launch_bounds__(256) void prep(const float* __restrict__ x1,
                                            const float* __restrict__ x2,
                                            _Float16* __restrict__ qn,
                                            _Float16* __restrict__ sn) {
    __shared__ float ssred[256];
    __shared__ half8 obuf[256];     // 32 descriptors x 8 pieces = 4KB
    int tid = threadIdx.x;
    int ml = tid & 31, cg = tid >> 5;     // 32 descriptors x 8 c-groups
    float v[8];
    half8* dstblk;
    int wz;
    if (blockIdx.x < BB * 14) {           // queries: 16 b x 14 p-tiles of 32
        int b = blockIdx.x / 14, pt = blockIdx.x % 14;
        int p = pt * 32 + ml;
        const float* src = x1 + (size_t)b * CC * HW + p;
        bool real = p < HW;
        #pragma unroll
        for (int i = 0; i < 8; ++i) v[i] = real ? src[(size_t)(cg * 8 + i) * HW] : 0.f;
        wz = cg;                                            // linear
        dstblk = (half8*)(qn + ((size_t)(b * QP + pt * 32)) * CC);
    } else {                              // supports: 10 n x 72 m-tiles of 32
        int sb = blockIdx.x - BB * 14;
        int n = sb / 72, mt = sb % 72;
        int m = mt * 32 + ml;
        const float* src = x2 + (size_t)n * CC * MM + m;
        bool real = m < MM;
        #pragma unroll
        for (int i = 0; i < 8; ++i) v[i] = real ? src[(size_t)(cg * 8 + i) * MM] : 0.f;
        wz = cg ^ (ml & 7);                                 // bank-swizzled piece
        dstblk = (half8*)(sn + ((size_t)(n * MP2 + mt * 32)) * CC);
    }
    float ss = 0.f;
    #pragma unroll
    for (int i = 0; i < 8; ++i) ss += v[i] * v[i];
    ssred[tid] = ss;
    __syncthreads();
    float tot = 0.f;
    #pragma unroll
    for (int j = 0; j < 8; ++j) tot += ssred[j * 32 + ml];
    float inv = 1.f / fmaxf(sqrtf(tot), 1e-12f);
    half8 h;
    #pragma unroll
    for (int i = 0; i < 8; ++i) h[i] = (_Float16)(v[i] * inv);
    obuf[ml * 8 + wz] = h;
    __syncthreads();
    dstblk[tid] = obuf[tid];              // 256 x 16B contiguous
}

// ---- main: per-(b,n,qgroup,mhalf) block. Swapped-operand MFMA D[m][q]:
// lanes own queries, 4 waves split m with PRIVATE self-staged LDS slices
// (zero in-loop barriers). TRIPLE-buffered, 2-deep counted-vmcnt prefetch:
// chunks c+1 and c+2 stay in flight while computing chunk c, hiding the
// L2 staging latency that capped round-1 at 38% MfmaUtil. 4 register-
// resident Q-tiles amortize each S-fragment read over 16 MFMAs. ----
__global__ __launch_bounds__(256, 4) void img2class_mfma(const _Float16* __restrict__ qn,
                                                         const _Float16* __restrict__ sn,
                                                         float* __restrict__ partial) {
    __shared__ half8 ldsv[3 * CH_T * 16 * 8];   // 3 bufs x 16KB; wave w owns 4KB of each
    _Float16* ldsh = (_Float16*)ldsv;
    char* lbase = (char*)ldsv;

    int mh = blockIdx.x & 1;
    int t  = blockIdx.x >> 1;
    int bn = t / 7, qg = t % 7;
    int b = bn / NCLS, n = bn % NCLS;
    int mtile0 = mh ? 72 : 0;

    int tid  = threadIdx.x;
    int wave = tid >> 6, lane = tid & 63;
    int col  = lane & 15, quad = lane >> 4;
    int q0 = qg * (NQT * 16);

    const char* sbase = (const char*)(sn + (size_t)n * MP2 * CC) + (size_t)mtile0 * 16 * CC * 2;
    int so   = wave * 4096 + lane * 16;   // global src offset within chunk
    int ldst = wave * 4096;               // lds dest base (wave-private slice)

    // prologue: chunks 0 and 1 -> bufs 0,1 (this wave's pair of m-tiles each)
    #pragma unroll
    for (int i = 0; i < 4; ++i)
        GLDS16(sbase + so + i * 1024, lbase + ldst + i * 1024);
    #pragma unroll
    for (int i = 0; i < 4; ++i)
        GLDS16(sbase + CH_B + so + i * 1024, lbase + CH_B + ldst + i * 1024);

    // Q fragments: 4 q-tiles x (k 0-31 | 32-63), register-resident whole kernel.
    // B-operand layout: col j = lane&15 (query), k = quad*8+i.
    const half8* Qp = (const half8*)(qn + ((size_t)(b * QP + q0 + col)) * CC) + quad;
    half8 Q0[NQT], Q1[NQT];
    #pragma unroll
    for (int qt = 0; qt < NQT; ++qt) {
        Q0[qt] = Qp[qt * 128];
        Q1[qt] = Qp[qt * 128 + 4];
    }

    // per-lane top-3 per q-tile (lane's q = q0 + qt*16 + col)
    float T0[NQT], T1[NQT], T2[NQT];
    #pragma unroll
    for (int qt = 0; qt < NQT; ++qt) { T0[qt] = -1.0e30f; T1[qt] = -1.0e30f; T2[qt] = -1.0e30f; }

    // S-fragment (A-operand) offsets within wave slice: row i = col (descriptor),
    // piece (quad | 4+quad) XOR-unswizzled by (row&7) == (col&7) for rows col, col+16
    int offE0 = col * CC + ((quad       ^ (col & 7)) << 3);
    int offE1 = col * CC + (((4 + quad) ^ (col & 7)) << 3);

    #pragma unroll
    for (int c = 0; c < NCH; ++c) {
        __builtin_amdgcn_sched_barrier(0);
        if (c + 2 < NCH) {
            const char* g = sbase + (size_t)(c + 2) * CH_B + so;
            char* l = lbase + ((c + 2) % 3) * CH_B + ldst;
            #pragma unroll
            for (int i = 0; i < 4; ++i)
                GLDS16(g + i * 1024, l + i * 1024);
            __builtin_amdgcn_sched_barrier(0);
            WAIT_VMCNT(8);     // {c+1, c+2} in flight; chunk c's 4 loads complete
        } else if (c + 1 < NCH) {
            WAIT_VMCNT(4);     // {c+1} in flight; chunk c resident
        } else {
            WAIT_VMCNT(0);
        }
        __builtin_amdgcn_sched_barrier(0);   // keep ds_reads below the waitcnt

        // waves 1-3 of the last half-1 chunk cover only fully-padded tiles (>=138)
        bool lastc = (mh == 1) && (c == NCH - 1);
        if (lastc && wave >= 1) continue;

        const _Float16* lw = ldsh + (c % 3) * (CH_T * 16 * CC) + wave * (32 * CC);
        half8 S0e = *(const half8*)(lw + offE0);
        half8 S1e = *(const half8*)(lw + offE1);
        half8 S0o = *(const half8*)(lw + offE0 + 16 * CC);
        half8 S1o = *(const half8*)(lw + offE1 + 16 * CC);

        // pad penalty (only last chunk of half1, wave 0: tile 137 rows m>=2205)
        int tE = mtile0 + c * CH_T + wave * 2;
        float pO0 = 0.f, pO1 = 0.f, pO2 = 0.f, pO3 = 0.f;
        if (lastc) {
            int mO = tE * 16 + 16 + quad * 4;
            pO0 = (mO + 0 >= MM) ? -1.0e30f : 0.f;
            pO1 = (mO + 1 >= MM) ? -1.0e30f : 0.f;
            pO2 = (mO + 2 >= MM) ? -1.0e30f : 0.f;
            pO3 = (mO + 3 >= MM) ? -1.0e30f : 0.f;
        }

        float4_ z = {0.f, 0.f, 0.f, 0.f};
        #pragma unroll
        for (int qt = 0; qt < NQT; ++qt) {
            // D[i=m][j=q]: rows quad*4+r are m within tile, col = q within tile
            float4_ ae = __builtin_amdgcn_mfma_f32_16x16x32_f16(S0e, Q0[qt], z, 0, 0, 0);
            ae = __builtin_amdgcn_mfma_f32_16x16x32_f16(S1e, Q1[qt], ae, 0, 0, 0);
            float4_ ao = __builtin_amdgcn_mfma_f32_16x16x32_f16(S0o, Q0[qt], z, 0, 0, 0);
            ao = __builtin_amdgcn_mfma_f32_16x16x32_f16(S1o, Q1[qt], ao, 0, 0, 0);
            if (lastc) { ao.x += pO0; ao.y += pO1; ao.z += pO2; ao.w += pO3; }
            // pair-max over adjacent tiles (m, m+16) — identical candidate
            // multiset to the verified kernels — then 3-op inserts
            float d0 = fmaxf(ae.x, ao.x);
            float d1 = fmaxf(ae.y, ao.y);
            float d2 = fmaxf(ae.z, ao.z);
            float d3 = fmaxf(ae.w, ao.w);
            ins3(d0, T0[qt], T1[qt], T2[qt]);
            ins3(d1, T0[qt], T1[qt], T2[qt]);
            ins3(d2, T0[qt], T1[qt], T2[qt]);
            ins3(d3, T0[qt], T1[qt], T2[qt]);
        }
    }

    // merge across the 4 quads (disjoint m rows, same q): 2-step butterfly
    #pragma unroll
    for (int step = 16; step <= 32; step <<= 1) {
        #pragma unroll
        for (int qt = 0; qt < NQT; ++qt) {
            float o0 = __shfl_xor(T0[qt], step);
            float o1 = __shfl_xor(T1[qt], step);
            float o2 = __shfl_xor(T2[qt], step);
            ins3(o0, T0[qt], T1[qt], T2[qt]);
            ins3(o1, T0[qt], T1[qt], T2[qt]);
            ins3(o2, T0[qt], T1[qt], T2[qt]);
        }
    }

    // dump per-wave per-q top-3 into this wave's (fully consumed) buf0 slice
    float* dumpW = (float*)(lbase + wave * 4096);
    if (quad == 0) {
        #pragma unroll
        for (int qt = 0; qt < NQT; ++qt) {
            float* dp = dumpW + (qt * 16 + col) * 3;
            dp[0] = T0[qt]; dp[1] = T1[qt]; dp[2] = T2[qt];
        }
    }
    __syncthreads();

    // cross-wave merge (waves hold disjoint m); partial layout unchanged
    if (tid < 64) {
        const float* d0 = (const float*)(lbase) + tid * 3;
        float a0 = d0[0], a1 = d0[1], a2 = d0[2];
        #pragma unroll
        for (int w = 1; w < 4; ++w) {
            const float* dw = (const float*)(lbase + w * 4096) + tid * 3;
            ins3(dw[0], a0, a1, a2);
            ins3(dw[1], a0, a1, a2);
            ins3(dw[2], a0, a1, a2);
        }
        float* pp = partial + ((size_t)((bn * 7 + qg) * 2 + mh) * 64 + tid) * 3;
        pp[0] = a0; pp[1] = a1; pp[2] = a2;
    }
}

// ---- merge the two m-halves per query, sum top-3, reduce over queries ----
__global__ __launch_bounds__(512) void merge_halves(const float* __restrict__ partial,
                                                    float* __restrict__ out) {
    __shared__ float red[512];
    int bn = blockIdx.x;
    int q  = threadIdx.x;
    float s = 0.f;
    if (q < HW) {
        int qg = q >> 6, ql = q & 63;
        const float* p0 = partial + ((size_t)((bn * 7 + qg) * 2 + 0) * 64 + ql) * 3;
        const float* p1 = partial + ((size_t)((bn * 7 + qg) * 2 + 1) * 64 + ql) * 3;
        float a0 = p0[0], a1 = p0[1], a2 = p0[2];
        ins3(p1[0], a0, a1, a2);
        ins3(p1[1], a0, a1, a2);
        ins3(p1[2], a0, a1, a2);
        s = a0 + a1 + a2;
    }
    red[q] = s;
    __syncthreads();
    #pragma unroll
    for (int stride = 256; stride >= 1; stride >>= 1) {
        if (q < stride) red[q] += red[q + stride];
        __syncthreads();
    }
    if (q == 0) out[bn] = red[0];
}

extern "C" void kernel_launch(void* const* d_in, const int* in_sizes, int n_in,
                              void* d_out, int out_size, void* d_ws, size_t ws_size,
                              hipStream_t stream) {
    const float* x1 = (const float*)d_in[0];   // [16,64,21,21]
    const float* x2 = (const float*)d_in[1];   // [10,64,2205]
    float* out = (float*)d_out;                // [16,10]

    _Float16* qn   = (_Float16*)d_ws;                  // 16*448*64 halves
    _Float16* sn   = qn + (size_t)BB * QP * CC;        // 10*2304*64 halves, swizzled
    float* partial = (float*)(sn + (size_t)NCLS * MP2 * CC);  // 2240*64*3 floats

    prep<<<BB * 14 + NCLS * 72, 256, 0, stream>>>(x1, x2, qn, sn);
    img2class_mfma<<<BB * NCLS * 7 * 2, 256, 0, stream>>>(qn, sn, partial);
    merge_halves<<<BB * NCLS, 512, 0, stream>>>(partial, out);
}